// Round 3
// baseline (59.145 us; speedup 1.0000x reference)
//
#include <hip/hip_runtime.h>

#define B_   4
#define CIN  64
#define COUT 64
#define H_   128
#define W_   128
#define HW   (H_*W_)
#define KK   9
#define PIX  (B_*H_*W_)    // 65536
#define BTILE 64           // pixels per block (4 waves x 16)
#define NBLK (PIX / BTILE) // 1024

typedef short bf16x8 __attribute__((ext_vector_type(8)));
typedef float f32x4  __attribute__((ext_vector_type(4)));
typedef int   i32x4  __attribute__((ext_vector_type(4)));
typedef unsigned int u32x4 __attribute__((ext_vector_type(4)));

__device__ __forceinline__ unsigned short f2bf(float f) {
    unsigned int u = __float_as_uint(f);
    u = (u + 0x7FFFu + ((u >> 16) & 1u)) >> 16;
    return (unsigned short)u;
}

// ---- Kernel 1: x (B,CIN,H,W) f32 -> xt (B,H,W,CIN) bf16 (channels-last) ----
__global__ __launch_bounds__(256) void k_transpose(const float* __restrict__ x,
                                                   unsigned short* __restrict__ xt) {
    __shared__ float lds[64 * 129];
    int bi = blockIdx.x;            // b*H + i
    int b = bi >> 7, i = bi & 127;
    int tid = threadIdx.x;
#pragma unroll
    for (int cc = 0; cc < 32; ++cc) {
        int c = cc * 2 + (tid >> 7);
        int w = tid & 127;
        lds[c * 129 + w] = x[((b * CIN + c) * H_ + i) * W_ + w];
    }
    __syncthreads();
#pragma unroll
    for (int q = 0; q < 32; ++q) {
        int c = tid & 63;
        int w = q * 4 + (tid >> 6);
        xt[((b * H_ + i) * W_ + w) * CIN + c] = f2bf(lds[c * 129 + w]);
    }
}

// ---- Kernel 2: weight (COUT,CIN,3,3) f32 -> B-fragment-ordered bf16 ----
// wtf[s][nt][lane][j] = W[n][c][kpos];  kg = s*32 + (lane>>4)*8 + j = kpos*64 + c
__global__ __launch_bounds__(256) void k_weight(const float* __restrict__ w,
                                                unsigned short* __restrict__ wtf) {
    int t = blockIdx.x * 256 + threadIdx.x;
    if (t >= 18 * 4 * 64 * 8) return;
    int j    = t & 7;
    int lane = (t >> 3) & 63;
    int nt   = (t >> 9) & 3;
    int s    = t >> 11;
    int kg   = s * 32 + ((lane >> 4) << 3) + j;
    int n    = nt * 16 + (lane & 15);
    int kpos = kg >> 6, c = kg & 63;
    wtf[t] = f2bf(w[(n * CIN + c) * 9 + kpos]);
}

// ---- Main: per-wave independent 16-pixel GEMM, zero-barrier main loop ----
__global__ __launch_bounds__(256, 4) void k_main(
    const unsigned short* __restrict__ xt,
    const float* __restrict__ offset,
    const float* __restrict__ mask,
    const unsigned short* __restrict__ wtf,
    const float* __restrict__ bias,
    float* __restrict__ out) {
    // meta: [wave][144] (i32x4 + f32x4) = 18432 B; reused as C-stage [64][68] f32
    __shared__ __align__(16) char smem[4 * 144 * 32];
    i32x4* meta_a = (i32x4*)smem;
    f32x4* meta_w = (f32x4*)(smem + 4 * 144 * 16);

    const int tid  = threadIdx.x;
    const int lane = tid & 63;
    const int wv   = tid >> 6;
    // XCD-aware swizzle: 1024 blocks, 8 XCDs -> XCD x owns contiguous 128-tile chunk
    const int tile = ((blockIdx.x & 7) << 7) + (blockIdx.x >> 3);
    const int g0   = tile * BTILE;
    const int b  = g0 >> 14;
    const int i  = (g0 >> 7) & 127;
    const int j0 = g0 & 127;       // 0 or 64

    // -------- phase 0: metadata, each wave computes its own 144 entries --------
    for (int e = lane; e < 144; e += 64) {
        int kp = e >> 4;           // 0..8
        int p  = e & 15;
        int j  = j0 + wv * 16 + p;
        int hw = i * W_ + j;
        float offi = offset[(b * 18 + 2 * kp) * HW + hw];
        float offj = offset[(b * 18 + 2 * kp + 1) * HW + hw];
        float msk  = mask[(b * KK + kp) * HW + hw];
        float ci = offi + (float)(i + kp / 3 - 1);
        float cj = offj + (float)(j + kp % 3 - 1);
        float fli = floorf(ci), flj = floorf(cj);
        float fi = ci - fli, fj = cj - flj;
        int li = (int)fli, lj = (int)flj;
        int li1 = li + 1, lj1 = lj + 1;
        float vy0 = (li  >= 0 && li  < H_) ? 1.f : 0.f;
        float vy1 = (li1 >= 0 && li1 < H_) ? 1.f : 0.f;
        float vx0 = (lj  >= 0 && lj  < W_) ? 1.f : 0.f;
        float vx1 = (lj1 >= 0 && lj1 < W_) ? 1.f : 0.f;
        int y0 = min(max(li,  0), H_ - 1), y1 = min(max(li1, 0), H_ - 1);
        int x0 = min(max(lj,  0), W_ - 1), x1 = min(max(lj1, 0), W_ - 1);
        float gi  = fi * msk;
        float gj  = fj * msk;
        float w11 = gi * fj;
        float w10 = gi - w11;
        float w01 = gj - w11;
        float w00 = msk - gi - gj + w11;
        i32x4 a; f32x4 w;
        a.x = (y0 * W_ + x0) * (CIN * 2); w.x = w00 * vy0 * vx0;
        a.y = (y0 * W_ + x1) * (CIN * 2); w.y = w01 * vy0 * vx1;
        a.z = (y1 * W_ + x0) * (CIN * 2); w.z = w10 * vy1 * vx0;
        a.w = (y1 * W_ + x1) * (CIN * 2); w.w = w11 * vy1 * vx1;
        meta_a[wv * 144 + e] = a;
        meta_w[wv * 144 + e] = w;
    }
    __syncthreads();

    // -------- main loop: gather+blend A in registers, 4 n-acc MFMAs --------
    f32x4 acc0 = {0.f,0.f,0.f,0.f}, acc1 = {0.f,0.f,0.f,0.f};
    f32x4 acc2 = {0.f,0.f,0.f,0.f}, acc3 = {0.f,0.f,0.f,0.f};
    const char* xb = (const char*)xt + (size_t)b * (HW * CIN * 2);
    const bf16x8* wp = (const bf16x8*)wtf;
    const int cb = (lane >> 4) * 16;     // channel-group byte offset in 128B pixel
#pragma unroll 3
    for (int kp = 0; kp < 9; ++kp) {
        i32x4 ao = meta_a[wv * 144 + kp * 16 + (lane & 15)];
        f32x4 wt = meta_w[wv * 144 + kp * 16 + (lane & 15)];
#pragma unroll
        for (int h = 0; h < 2; ++h) {
            int cof = cb + h * 64;
            u32x4 q00 = *(const u32x4*)(xb + ao.x + cof);
            u32x4 q01 = *(const u32x4*)(xb + ao.y + cof);
            u32x4 q10 = *(const u32x4*)(xb + ao.z + cof);
            u32x4 q11 = *(const u32x4*)(xb + ao.w + cof);
            int s = kp * 2 + h;
            bf16x8 b0 = wp[(s * 4 + 0) * 64 + lane];
            bf16x8 b1 = wp[(s * 4 + 1) * 64 + lane];
            bf16x8 b2 = wp[(s * 4 + 2) * 64 + lane];
            bf16x8 b3 = wp[(s * 4 + 3) * 64 + lane];
            u32x4 po;
#pragma unroll
            for (int q = 0; q < 4; ++q) {
                float l00 = __uint_as_float(q00[q] << 16);
                float l01 = __uint_as_float(q01[q] << 16);
                float l10 = __uint_as_float(q10[q] << 16);
                float l11 = __uint_as_float(q11[q] << 16);
                float h00 = __uint_as_float(q00[q] & 0xFFFF0000u);
                float h01 = __uint_as_float(q01[q] & 0xFFFF0000u);
                float h10 = __uint_as_float(q10[q] & 0xFFFF0000u);
                float h11 = __uint_as_float(q11[q] & 0xFFFF0000u);
                float rl = wt.x * l00 + wt.y * l01 + wt.z * l10 + wt.w * l11;
                float rh = wt.x * h00 + wt.y * h01 + wt.z * h10 + wt.w * h11;
                po[q] = __builtin_amdgcn_perm(__float_as_uint(rh) + 0x8000u,
                                              __float_as_uint(rl) + 0x8000u,
                                              0x07060302u);
            }
            bf16x8 af;
            *(u32x4*)&af = po;
            acc0 = __builtin_amdgcn_mfma_f32_16x16x32_bf16(af, b0, acc0, 0, 0, 0);
            acc1 = __builtin_amdgcn_mfma_f32_16x16x32_bf16(af, b1, acc1, 0, 0, 0);
            acc2 = __builtin_amdgcn_mfma_f32_16x16x32_bf16(af, b2, acc2, 0, 0, 0);
            acc3 = __builtin_amdgcn_mfma_f32_16x16x32_bf16(af, b3, acc3, 0, 0, 0);
        }
    }

    // -------- epilogue: stage C in LDS (pad 68), coalesced block-write --------
    __syncthreads();                     // meta region being reused
    float* cst = (float*)smem;           // [64 couts][68] f32, 17408 B
    const int nn = lane & 15;
    const int pm = wv * 16 + ((lane >> 4) << 2);
    {
        f32x4 v0 = acc0, v1 = acc1, v2 = acc2, v3 = acc3;
        float bs0 = bias[nn], bs1 = bias[16 + nn], bs2 = bias[32 + nn], bs3 = bias[48 + nn];
#pragma unroll
        for (int r = 0; r < 4; ++r) { v0[r] += bs0; v1[r] += bs1; v2[r] += bs2; v3[r] += bs3; }
        *(f32x4*)&cst[(nn)      * 68 + pm] = v0;
        *(f32x4*)&cst[(16 + nn) * 68 + pm] = v1;
        *(f32x4*)&cst[(32 + nn) * 68 + pm] = v2;
        *(f32x4*)&cst[(48 + nn) * 68 + pm] = v3;
    }
    __syncthreads();
    const int cl = tid >> 4;             // 0..15
    const int px = (tid & 15) * 4;       // 0..60
    const size_t obase = (size_t)b * (COUT * HW) + i * W_ + j0;
#pragma unroll
    for (int c4 = 0; c4 < 4; ++c4) {
        int cout = c4 * 16 + cl;
        f32x4 vv = *(const f32x4*)&cst[cout * 68 + px];
        *(f32x4*)&out[obase + (size_t)cout * HW + px] = vv;
    }
}

extern "C" void kernel_launch(void* const* d_in, const int* in_sizes, int n_in,
                              void* d_out, int out_size, void* d_ws, size_t ws_size,
                              hipStream_t stream) {
    const float* x      = (const float*)d_in[0];
    const float* offset = (const float*)d_in[1];
    const float* mask   = (const float*)d_in[2];
    const float* weight = (const float*)d_in[3];
    const float* bias   = (const float*)d_in[4];
    float* out = (float*)d_out;
    unsigned short* xt  = (unsigned short*)d_ws;
    unsigned short* wtf = xt + (size_t)B_ * H_ * W_ * CIN;   // +8 MB

    k_transpose<<<B_ * H_, 256, 0, stream>>>(x, xt);
    k_weight<<<144, 256, 0, stream>>>(weight, wtf);
    k_main<<<NBLK, 256, 0, stream>>>(xt, offset, mask, wtf, bias, out);
}

// Round 4
// 56.385 us; speedup vs baseline: 1.0489x; 1.0489x over previous
//
#include <hip/hip_runtime.h>

#define B_   4
#define CIN  64
#define COUT 64
#define H_   128
#define W_   128
#define HW   (H_*W_)
#define KK   9
#define PIX  (B_*H_*W_)    // 65536
#define BTILE 64           // pixels per block (4 waves x 16)
#define NBLK (PIX / BTILE) // 1024

typedef short bf16x8 __attribute__((ext_vector_type(8)));
typedef float f32x4  __attribute__((ext_vector_type(4)));
typedef float f32x2  __attribute__((ext_vector_type(2)));
typedef int   i32x4  __attribute__((ext_vector_type(4)));
typedef unsigned int u32;
typedef unsigned int u32x4 __attribute__((ext_vector_type(4)));

__device__ __forceinline__ unsigned short f2bf(float f) {
    unsigned int u = __float_as_uint(f);
    u = (u + 0x7FFFu + ((u >> 16) & 1u)) >> 16;
    return (unsigned short)u;
}

// ---- Kernel 1: x (B,CIN,H,W) f32 -> xt (B,H,W,CIN) bf16 (channels-last) ----
__global__ __launch_bounds__(256) void k_transpose(const float* __restrict__ x,
                                                   unsigned short* __restrict__ xt) {
    __shared__ float lds[64 * 129];
    int bi = blockIdx.x;            // b*H + i
    int b = bi >> 7, i = bi & 127;
    int tid = threadIdx.x;
#pragma unroll
    for (int cc = 0; cc < 32; ++cc) {
        int c = cc * 2 + (tid >> 7);
        int w = tid & 127;
        lds[c * 129 + w] = x[((b * CIN + c) * H_ + i) * W_ + w];
    }
    __syncthreads();
#pragma unroll
    for (int q = 0; q < 32; ++q) {
        int c = tid & 63;
        int w = q * 4 + (tid >> 6);
        xt[((b * H_ + i) * W_ + w) * CIN + c] = f2bf(lds[c * 129 + w]);
    }
}

// ---- Kernel 2: weight (COUT,CIN,3,3) f32 -> B-fragment-ordered bf16 ----
// wtf[s][nt][lane][j] = W[n][c][kpos];  kg = s*32 + (lane>>4)*8 + j = kpos*64 + c
__global__ __launch_bounds__(256) void k_weight(const float* __restrict__ w,
                                                unsigned short* __restrict__ wtf) {
    int t = blockIdx.x * 256 + threadIdx.x;
    if (t >= 18 * 4 * 64 * 8) return;
    int j    = t & 7;
    int lane = (t >> 3) & 63;
    int nt   = (t >> 9) & 3;
    int s    = t >> 11;
    int kg   = s * 32 + ((lane >> 4) << 3) + j;
    int n    = nt * 16 + (lane & 15);
    int kpos = kg >> 6, c = kg & 63;
    wtf[t] = f2bf(w[(n * CIN + c) * 9 + kpos]);
}

struct Meta { i32x4 a; f32x4 w; };

// ---- Main: per-wave 16-pixel GEMM, registered meta, 3-deep SW pipeline ----
__global__ __launch_bounds__(256, 3) void k_main(
    const unsigned short* __restrict__ xt,
    const float* __restrict__ offset,
    const float* __restrict__ mask,
    const unsigned short* __restrict__ wtf,
    const float* __restrict__ bias,
    float* __restrict__ out) {
    __shared__ __align__(16) float cst[COUT * 68];   // C staging only, 17.4 KB

    const int tid  = threadIdx.x;
    const int lane = tid & 63;
    const int wv   = tid >> 6;
    // XCD-aware swizzle: 1024 blocks, 8 XCDs -> XCD x owns contiguous 128-tile chunk
    const int tile = ((blockIdx.x & 7) << 7) + (blockIdx.x >> 3);
    const int g0   = tile * BTILE;
    const int b  = g0 >> 14;
    const int i  = (g0 >> 7) & 127;
    const int j0 = g0 & 127;
    const int p  = lane & 15;              // this lane's pixel within wave tile
    const int j  = j0 + wv * 16 + p;
    const int cof = (lane >> 4) << 4;      // channel-group byte offset

    const float* offp = offset + (size_t)b * 18 * HW + i * W_ + j;
    const float* mskp = mask   + (size_t)b * 9  * HW + i * W_ + j;
    const char*  xb   = (const char*)xt + (size_t)b * (HW * CIN * 2);
    const bf16x8* wp  = (const bf16x8*)wtf;

    float oi[3], oj[3], om[3];
    Meta  mt[3];
    u32x4 G[2][4];
    bf16x8 Bf[2][4];
    f32x4 acc0 = {0,0,0,0}, acc1 = {0,0,0,0}, acc2 = {0,0,0,0}, acc3 = {0,0,0,0};

#define LOAD_OFF(kp, sl) do { \
    oi[sl] = offp[(2*(kp))*HW]; \
    oj[sl] = offp[(2*(kp)+1)*HW]; \
    om[sl] = mskp[(kp)*HW]; } while(0)

#define CALC_META(kp, sl) do { \
    float ci = oi[sl] + (float)(i + (kp)/3 - 1); \
    float cj = oj[sl] + (float)(j + (kp)%3 - 1); \
    float msk = om[sl]; \
    float fli = floorf(ci), flj = floorf(cj); \
    float fi = ci - fli, fj = cj - flj; \
    int li = (int)fli, lj = (int)flj; \
    int li1 = li + 1, lj1 = lj + 1; \
    float vy0 = (li  >= 0 && li  < H_) ? 1.f : 0.f; \
    float vy1 = (li1 >= 0 && li1 < H_) ? 1.f : 0.f; \
    float vx0 = (lj  >= 0 && lj  < W_) ? 1.f : 0.f; \
    float vx1 = (lj1 >= 0 && lj1 < W_) ? 1.f : 0.f; \
    int y0 = min(max(li,  0), H_-1), y1 = min(max(li1, 0), H_-1); \
    int x0 = min(max(lj,  0), W_-1), x1 = min(max(lj1, 0), W_-1); \
    float gi = fi * msk, gj = fj * msk; \
    float w11 = gi * fj; \
    mt[sl].w.x = (msk - gi - gj + w11) * vy0 * vx0; \
    mt[sl].w.y = (gj - w11) * vy0 * vx1; \
    mt[sl].w.z = (gi - w11) * vy1 * vx0; \
    mt[sl].w.w = w11 * vy1 * vx1; \
    mt[sl].a.x = (y0 * W_ + x0) * (CIN*2); \
    mt[sl].a.y = (y0 * W_ + x1) * (CIN*2); \
    mt[sl].a.z = (y1 * W_ + x0) * (CIN*2); \
    mt[sl].a.w = (y1 * W_ + x1) * (CIN*2); } while(0)

#define ISSUE_G(s, gs) do { \
    const Meta& m = mt[((s)>>1) % 3]; \
    int c = cof + ((s)&1) * 64; \
    G[gs][0] = *(const u32x4*)(xb + m.a.x + c); \
    G[gs][1] = *(const u32x4*)(xb + m.a.y + c); \
    G[gs][2] = *(const u32x4*)(xb + m.a.z + c); \
    G[gs][3] = *(const u32x4*)(xb + m.a.w + c); } while(0)

#define ISSUE_B(s, gs) do { \
    Bf[gs][0] = wp[((s)*4+0)*64 + lane]; \
    Bf[gs][1] = wp[((s)*4+1)*64 + lane]; \
    Bf[gs][2] = wp[((s)*4+2)*64 + lane]; \
    Bf[gs][3] = wp[((s)*4+3)*64 + lane]; } while(0)

#define BLEND_MFMA(s, gs) do { \
    const f32x4 w4 = mt[((s)>>1) % 3].w; \
    f32x2 wx = {w4.x, w4.x}, wy = {w4.y, w4.y}; \
    f32x2 wz = {w4.z, w4.z}, ww = {w4.w, w4.w}; \
    u32x4 po; \
    _Pragma("unroll") \
    for (int q = 0; q < 4; ++q) { \
        f32x2 c00 = {__uint_as_float(G[gs][0][q] << 16), __uint_as_float(G[gs][0][q] & 0xFFFF0000u)}; \
        f32x2 c01 = {__uint_as_float(G[gs][1][q] << 16), __uint_as_float(G[gs][1][q] & 0xFFFF0000u)}; \
        f32x2 c10 = {__uint_as_float(G[gs][2][q] << 16), __uint_as_float(G[gs][2][q] & 0xFFFF0000u)}; \
        f32x2 c11 = {__uint_as_float(G[gs][3][q] << 16), __uint_as_float(G[gs][3][q] & 0xFFFF0000u)}; \
        f32x2 r = wx * c00 + wy * c01 + wz * c10 + ww * c11; \
        po[q] = __builtin_amdgcn_perm(__float_as_uint(r.y) + 0x8000u, \
                                      __float_as_uint(r.x) + 0x8000u, 0x07060302u); \
    } \
    bf16x8 af; *(u32x4*)&af = po; \
    acc0 = __builtin_amdgcn_mfma_f32_16x16x32_bf16(af, Bf[gs][0], acc0, 0, 0, 0); \
    acc1 = __builtin_amdgcn_mfma_f32_16x16x32_bf16(af, Bf[gs][1], acc1, 0, 0, 0); \
    acc2 = __builtin_amdgcn_mfma_f32_16x16x32_bf16(af, Bf[gs][2], acc2, 0, 0, 0); \
    acc3 = __builtin_amdgcn_mfma_f32_16x16x32_bf16(af, Bf[gs][3], acc3, 0, 0, 0); } while(0)

    // ---- prologue: fill the pipeline ----
    LOAD_OFF(0, 0); LOAD_OFF(1, 1); LOAD_OFF(2, 2);
    CALC_META(0, 0); CALC_META(1, 1);
    ISSUE_G(0, 0); ISSUE_B(0, 0);

    // ---- steady state: per s-body (s = kp*2 + h):
    //   issue G/B for s+1 (meta ready 1 body ahead)
    //   h==0: issue off-loads kp+3;  h==1: compute meta kp+2
    //   blend + 4 MFMA on s (gathers issued 1 body ago)
#pragma unroll
    for (int s = 0; s < 18; ++s) {
        const int kp = s >> 1, h = s & 1;
        if (s + 1 < 18) { ISSUE_G(s + 1, (s + 1) & 1); ISSUE_B(s + 1, (s + 1) & 1); }
        if (h == 0 && kp + 3 <= 8) LOAD_OFF(kp + 3, (kp + 3) % 3);
        if (h == 1 && kp + 2 <= 8) CALC_META(kp + 2, (kp + 2) % 3);
        BLEND_MFMA(s, s & 1);
    }

    // ---- epilogue: stage C in LDS (pad 68), coalesced nontemporal write ----
    {
        f32x4 v0 = acc0, v1 = acc1, v2 = acc2, v3 = acc3;
        float bs0 = bias[p], bs1 = bias[16 + p], bs2 = bias[32 + p], bs3 = bias[48 + p];
#pragma unroll
        for (int r = 0; r < 4; ++r) { v0[r] += bs0; v1[r] += bs1; v2[r] += bs2; v3[r] += bs3; }
        const int pm = wv * 16 + ((lane >> 4) << 2);
        *(f32x4*)&cst[(p)      * 68 + pm] = v0;
        *(f32x4*)&cst[(16 + p) * 68 + pm] = v1;
        *(f32x4*)&cst[(32 + p) * 68 + pm] = v2;
        *(f32x4*)&cst[(48 + p) * 68 + pm] = v3;
    }
    __syncthreads();
    const int cl = tid >> 4;             // 0..15
    const int px = (tid & 15) * 4;       // 0..60
    const size_t obase = (size_t)b * (COUT * HW) + i * W_ + j0;
#pragma unroll
    for (int c4 = 0; c4 < 4; ++c4) {
        int cout = c4 * 16 + cl;
        f32x4 vv = *(const f32x4*)&cst[cout * 68 + px];
        __builtin_nontemporal_store(vv, (f32x4*)&out[obase + (size_t)cout * HW + px]);
    }
}

extern "C" void kernel_launch(void* const* d_in, const int* in_sizes, int n_in,
                              void* d_out, int out_size, void* d_ws, size_t ws_size,
                              hipStream_t stream) {
    const float* x      = (const float*)d_in[0];
    const float* offset = (const float*)d_in[1];
    const float* mask   = (const float*)d_in[2];
    const float* weight = (const float*)d_in[3];
    const float* bias   = (const float*)d_in[4];
    float* out = (float*)d_out;
    unsigned short* xt  = (unsigned short*)d_ws;
    unsigned short* wtf = xt + (size_t)B_ * H_ * W_ * CIN;   // +8 MB

    k_transpose<<<B_ * H_, 256, 0, stream>>>(x, xt);
    k_weight<<<144, 256, 0, stream>>>(weight, wtf);
    k_main<<<NBLK, 256, 0, stream>>>(xt, offset, mask, wtf, bias, out);
}